// Round 1
// baseline (90.132 us; speedup 1.0000x reference)
//
#include <hip/hip_runtime.h>

// Problem constants (from reference):
constexpr int N_ = 64, C_ = 3, H_ = 345, W_ = 456;
constexpr int HW_ = H_ * W_;
constexpr long long TOTAL_PIX = (long long)N_ * HW_;

__global__ __launch_bounds__(256) void grid_sample_kernel(
    const float* __restrict__ x,      // [N,C,H,W]
    const float* __restrict__ theta,  // [N,2,3]
    float* __restrict__ out)          // [N,C,H,W]
{
    int idx = blockIdx.x * blockDim.x + threadIdx.x;
    if (idx >= (int)TOTAL_PIX) return;

    int n   = idx / HW_;
    int rem = idx - n * HW_;
    int h   = rem / W_;
    int w   = rem - h * W_;

    // theta row for this batch
    const float* t = theta + n * 6;
    float t00 = t[0], t01 = t[1], t02 = t[2];
    float t10 = t[3], t11 = t[4], t12 = t[5];

    // _gs_linspace(W)[w] and _gs_linspace(H)[h], symmetric fp32 construction
    const float stepx  = 2.0f / (float)W_;
    const float startx = -(1.0f - 1.0f / (float)W_);
    float xs = (2 * w < W_) ? ((float)w * stepx + startx)
                            : (-startx - (float)(W_ - 1 - w) * stepx);

    const float stepy  = 2.0f / (float)H_;
    const float starty = -(1.0f - 1.0f / (float)H_);
    float ys = (2 * h < H_) ? ((float)h * stepy + starty)
                            : (-starty - (float)(H_ - 1 - h) * stepy);

    // grid = base . theta  (gx, gy)
    float gx = xs * t00 + ys * t01 + t02;
    float gy = xs * t10 + ys * t11 + t12;

    // unnormalize (align_corners=False)
    float ix = gx * ((float)W_ * 0.5f) + ((float)(W_ - 1)) * 0.5f;
    float iy = gy * ((float)H_ * 0.5f) + ((float)(H_ - 1)) * 0.5f;

    float x0f = floorf(ix), y0f = floorf(iy);
    int   x0  = (int)x0f,   y0  = (int)y0f;
    float fx  = ix - x0f,   fy  = iy - y0f;      // in [0,1)
    float gxc = 1.0f - fx,  gyc = 1.0f - fy;

    float w00 = gxc * gyc;   // (x0,y0)
    float w10 = fx  * gyc;   // (x1,y0)
    float w01 = gxc * fy;    // (x0,y1)
    float w11 = fx  * fy;    // (x1,y1)

    const float* xn = x + (size_t)n * C_ * HW_;
    float acc0 = 0.0f, acc1 = 0.0f, acc2 = 0.0f;

#define CORNER(xi, yi, wt)                                            \
    if ((unsigned)(xi) < (unsigned)W_ && (unsigned)(yi) < (unsigned)H_) { \
        int off = (yi) * W_ + (xi);                                   \
        acc0 += xn[off] * (wt);                                       \
        acc1 += xn[HW_ + off] * (wt);                                 \
        acc2 += xn[2 * HW_ + off] * (wt);                             \
    }

    CORNER(x0,     y0,     w00)
    CORNER(x0 + 1, y0,     w10)
    CORNER(x0,     y0 + 1, w01)
    CORNER(x0 + 1, y0 + 1, w11)
#undef CORNER

    float* on = out + (size_t)n * C_ * HW_ + rem;
    on[0]        = acc0;
    on[HW_]      = acc1;
    on[2 * HW_]  = acc2;
}

extern "C" void kernel_launch(void* const* d_in, const int* in_sizes, int n_in,
                              void* d_out, int out_size, void* d_ws, size_t ws_size,
                              hipStream_t stream) {
    const float* x     = (const float*)d_in[0];
    const float* theta = (const float*)d_in[1];
    float* out = (float*)d_out;

    int total  = (int)TOTAL_PIX;
    int block  = 256;
    int blocks = (total + block - 1) / block;
    grid_sample_kernel<<<blocks, block, 0, stream>>>(x, theta, out);
}

// Round 2
// 82.115 us; speedup vs baseline: 1.0976x; 1.0976x over previous
//
#include <hip/hip_runtime.h>

// affine_grid + grid_sample (bilinear, zeros, align_corners=False)
// N=64, C=3, H=345, W=456, fp32.
constexpr int N_ = 64, C_ = 3, H_ = 345, W_ = 456;
constexpr int HW_ = H_ * W_;

constexpr int TW = 32, TH = 8;                    // output tile per 256-thread block
constexpr int TX = (W_ + TW - 1) / TW;            // 15
constexpr int TY = (H_ + TH - 1) / TH;            // 44
constexpr int TILES = TX * TY;                    // 660
constexpr int MAXC = 48, MAXR = 20;               // staged source region capacity

__device__ __forceinline__ float gs_x(int w) {
    const float step  = 2.0f / (float)W_;
    const float start = -(1.0f - 1.0f / (float)W_);
    return (2 * w < W_) ? ((float)w * step + start)
                        : (-start - (float)(W_ - 1 - w) * step);
}
__device__ __forceinline__ float gs_y(int h) {
    const float step  = 2.0f / (float)H_;
    const float start = -(1.0f - 1.0f / (float)H_);
    return (2 * h < H_) ? ((float)h * step + start)
                        : (-start - (float)(H_ - 1 - h) * step);
}

__global__ __launch_bounds__(256) void gs_tiled(
    const float* __restrict__ x,      // [N,3,H,W]
    const float* __restrict__ theta,  // [N,2,3]
    float* __restrict__ out)          // [N,3,H,W]
{
    __shared__ float lds[3 * MAXR * MAXC];

    // XCD-affine decomposition: batch n runs only on XCD n%8 (blockIdx%8 ~ XCD).
    int b   = blockIdx.x;
    int xcd = b & 7;
    int i   = b >> 3;                 // [0, 8*TILES) per xcd
    int bg  = i / TILES;              // 0..7
    int tile = i - bg * TILES;
    int n   = xcd + 8 * bg;

    int ty = tile / TX;
    int tx = tile - ty * TX;
    int w0 = tx * TW, h0 = ty * TH;

    const float* t = theta + n * 6;
    float t00 = t[0], t01 = t[1], t02 = t[2];
    float t10 = t[3], t11 = t[4], t12 = t[5];

    const float halfW = 0.5f * (float)W_, cW = 0.5f * (float)(W_ - 1);
    const float halfH = 0.5f * (float)H_, cH = 0.5f * (float)(H_ - 1);

    // Source bbox of this tile (affine in monotone xs,ys -> extremes at corners).
    int we = min(w0 + TW - 1, W_ - 1);
    int he = min(h0 + TH - 1, H_ - 1);
    float xsl = gs_x(w0), xsh = gs_x(we);
    float ysl = gs_y(h0), ysh = gs_y(he);

    float ixa = (xsl * t00 + ysl * t01 + t02) * halfW + cW;
    float ixb = (xsh * t00 + ysl * t01 + t02) * halfW + cW;
    float ixc = (xsl * t00 + ysh * t01 + t02) * halfW + cW;
    float ixd = (xsh * t00 + ysh * t01 + t02) * halfW + cW;
    float iya = (xsl * t10 + ysl * t11 + t12) * halfH + cH;
    float iyb = (xsh * t10 + ysl * t11 + t12) * halfH + cH;
    float iyc = (xsl * t10 + ysh * t11 + t12) * halfH + cH;
    float iyd = (xsh * t10 + ysh * t11 + t12) * halfH + cH;

    float minix = fminf(fminf(ixa, ixb), fminf(ixc, ixd));
    float maxix = fmaxf(fmaxf(ixa, ixb), fmaxf(ixc, ixd));
    float miniy = fminf(fminf(iya, iyb), fminf(iyc, iyd));
    float maxiy = fmaxf(fmaxf(iya, iyb), fmaxf(iyc, iyd));

    int x_lo = (int)floorf(minix), x_hi = (int)floorf(maxix) + 1;
    int y_lo = (int)floorf(miniy), y_hi = (int)floorf(maxiy) + 1;
    int xc0 = max(x_lo, 0), xc1 = min(x_hi, W_ - 1);
    int yc0 = max(y_lo, 0), yc1 = min(y_hi, H_ - 1);
    int colsC = xc1 - xc0 + 1, rowsC = yc1 - yc0 + 1;

    bool use_lds = (colsC > 0 && rowsC > 0 && colsC <= MAXC && rowsC <= MAXR);

    const float* xn = x + (size_t)n * 3 * HW_;
    int tid = threadIdx.x;

    if (use_lds) {
        // Dense coalesced staging: 64 lanes sweep a source row segment.
        int colT = tid & 63, rowT = tid >> 6;   // 4 row-streams
        if (colT < colsC) {
            for (int c = 0; c < 3; ++c) {
                const float* src = xn + c * HW_ + xc0 + colT;
                float* dst = &lds[c * (MAXR * MAXC) + colT];
                for (int r = rowT; r < rowsC; r += 4)
                    dst[r * MAXC] = src[(yc0 + r) * W_];
            }
        }
        __syncthreads();   // block-uniform branch: safe
    }

    int tw = tid & 31, th = tid >> 5;
    int w = w0 + tw, h = h0 + th;
    if (w >= W_ || h >= H_) return;            // after the only barrier

    float xs = gs_x(w), ys = gs_y(h);
    float ix = (xs * t00 + ys * t01 + t02) * halfW + cW;
    float iy = (xs * t10 + ys * t11 + t12) * halfH + cH;

    float x0f = floorf(ix), y0f = floorf(iy);
    int   X0 = (int)x0f,    Y0 = (int)y0f;
    float fx = ix - x0f,    fy = iy - y0f;
    float gx1 = 1.0f - fx,  gy1 = 1.0f - fy;
    float w00 = gx1 * gy1, w10 = fx * gy1, w01 = gx1 * fy, w11 = fx * fy;

    float a0 = 0.0f, a1 = 0.0f, a2 = 0.0f;

    if (use_lds) {
#define CORN(xi, yi, wt)                                                     \
        if ((unsigned)(xi) < (unsigned)W_ && (unsigned)(yi) < (unsigned)H_) {\
            int lr = (yi) - yc0, lc = (xi) - xc0;                            \
            const float* p = &lds[lr * MAXC + lc];                           \
            a0 += p[0] * (wt);                                               \
            a1 += p[MAXR * MAXC] * (wt);                                     \
            a2 += p[2 * MAXR * MAXC] * (wt);                                 \
        }
        CORN(X0,     Y0,     w00)
        CORN(X0 + 1, Y0,     w10)
        CORN(X0,     Y0 + 1, w01)
        CORN(X0 + 1, Y0 + 1, w11)
#undef CORN
    } else {
#define CORNG(xi, yi, wt)                                                    \
        if ((unsigned)(xi) < (unsigned)W_ && (unsigned)(yi) < (unsigned)H_) {\
            int off = (yi) * W_ + (xi);                                      \
            a0 += xn[off] * (wt);                                            \
            a1 += xn[HW_ + off] * (wt);                                      \
            a2 += xn[2 * HW_ + off] * (wt);                                  \
        }
        CORNG(X0,     Y0,     w00)
        CORNG(X0 + 1, Y0,     w10)
        CORNG(X0,     Y0 + 1, w01)
        CORNG(X0 + 1, Y0 + 1, w11)
#undef CORNG
    }

    size_t o = (size_t)n * 3 * HW_ + (size_t)h * W_ + w;
    out[o]           = a0;
    out[o + HW_]     = a1;
    out[o + 2 * HW_] = a2;
}

extern "C" void kernel_launch(void* const* d_in, const int* in_sizes, int n_in,
                              void* d_out, int out_size, void* d_ws, size_t ws_size,
                              hipStream_t stream) {
    const float* x     = (const float*)d_in[0];
    const float* theta = (const float*)d_in[1];
    float* out = (float*)d_out;

    int blocks = N_ * TILES;   // 42240, divisible by 8
    gs_tiled<<<blocks, 256, 0, stream>>>(x, theta, out);
}